// Round 1
// baseline (145.143 us; speedup 1.0000x reference)
//
#include <hip/hip_runtime.h>
#include <cmath>

// SSIM stability loss: 1 - mean(SSIM(x, y)) with 11x11 Gaussian window (sigma=1.5),
// zero ("SAME") padding, fp32, images 32 x 1 x 512 x 512.
//
// Structure: fused single pass. Tile = 128 wide x 32 tall per 256-thread block.
// Thread t owns output column (t & 127) and a strip of 16 output rows
// (strip = t >> 7). Inputs staged in LDS with 5-px halo; horizontal 11-tap conv
// computed per H-row from LDS; vertical 11-tap conv done purely in registers by
// scatter-accumulating each H row into the 16 per-thread output accumulators
// (5 channels each: mu_x, mu_y, E[xx], E[yy], E[xy]).
// Per-block partial sums -> d_ws (2048 doubles, no atomics), second kernel reduces.

#define IMG     512
#define TILE_W  128
#define TILE_H  32
#define R_PER   16              // output rows per thread
#define HALO    5
#define IN_W    (TILE_W + 10)   // 138
#define IN_H    (TILE_H + 10)   // 42
#define NBLOCKS (4 * 16 * 32)   // 2048
#define NPIX    8388608.0       // 32*512*512

struct GaussW { float w[11]; };

__global__ __launch_bounds__(256)
void ssim_fused_kernel(const float* __restrict__ x, const float* __restrict__ y,
                       double* __restrict__ partial, GaussW gw) {
    __shared__ float sx[IN_H][IN_W];
    __shared__ float sy[IN_H][IN_W];
    __shared__ float wavesum[4];

    const int tid = threadIdx.x;
    const int c0 = blockIdx.x * TILE_W;
    const int r0 = blockIdx.y * TILE_H;
    const size_t img_off = (size_t)blockIdx.z * (IMG * IMG);
    const float* __restrict__ xb = x + img_off;
    const float* __restrict__ yb = y + img_off;

    // ---- Phase A: stage input tile + halo into LDS (zero padding outside) ----
    for (int idx = tid; idx < IN_H * IN_W; idx += 256) {
        int r = idx / IN_W;
        int c = idx - r * IN_W;
        int gr = r0 - HALO + r;
        int gc = c0 - HALO + c;
        float vx = 0.f, vy = 0.f;
        if (gr >= 0 && gr < IMG && gc >= 0 && gc < IMG) {
            int g = gr * IMG + gc;
            vx = xb[g];
            vy = yb[g];
        }
        sx[r][c] = vx;
        sy[r][c] = vy;
    }
    __syncthreads();

    const int ci    = tid & (TILE_W - 1);  // column within tile; taps ci..ci+10
    const int strip = tid >> 7;            // 0 or 1
    const int rbase = strip * R_PER;       // LDS row offset of this strip's H rows

    float acc[R_PER][5];
    #pragma unroll
    for (int j = 0; j < R_PER; ++j) {
        #pragma unroll
        for (int ch = 0; ch < 5; ++ch) acc[j][ch] = 0.f;
    }

    // ---- Phase B: stream H rows (horizontal conv), scatter into vertical accs ----
    #pragma unroll
    for (int r = 0; r < R_PER + 10; ++r) {
        float hx = 0.f, hy = 0.f, hxx = 0.f, hyy = 0.f, hxy = 0.f;
        #pragma unroll
        for (int k = 0; k < 11; ++k) {
            float wk = gw.w[k];
            float a = sx[rbase + r][ci + k];
            float b = sy[rbase + r][ci + k];
            float ta = wk * a;
            float tb = wk * b;
            hx += ta;
            hy += tb;
            hxx = fmaf(ta, a, hxx);
            hyy = fmaf(tb, b, hyy);
            hxy = fmaf(ta, b, hxy);
        }
        // Output row j (strip-local) uses H rows j..j+10 with weight w[r - j].
        #pragma unroll
        for (int j = 0; j < R_PER; ++j) {
            const int k = r - j;
            if (k >= 0 && k < 11) {   // folds at compile time (r, j both constants)
                float wv = gw.w[k];
                acc[j][0] = fmaf(wv, hx,  acc[j][0]);
                acc[j][1] = fmaf(wv, hy,  acc[j][1]);
                acc[j][2] = fmaf(wv, hxx, acc[j][2]);
                acc[j][3] = fmaf(wv, hyy, acc[j][3]);
                acc[j][4] = fmaf(wv, hxy, acc[j][4]);
            }
        }
    }

    // ---- Phase C: SSIM per pixel, thread-local sum ----
    const float C1 = 1e-4f;   // (0.01*1)^2
    const float C2 = 9e-4f;   // (0.03*1)^2
    float lsum = 0.f;
    #pragma unroll
    for (int j = 0; j < R_PER; ++j) {
        float mx  = acc[j][0], my  = acc[j][1];
        float exx = acc[j][2], eyy = acc[j][3], exy = acc[j][4];
        float mxx = mx * mx, myy = my * my, mxy = mx * my;
        float sxx = exx - mxx, syy = eyy - myy, sxy = exy - mxy;
        float num = (2.f * mxy + C1) * (2.f * sxy + C2);
        float den = (mxx + myy + C1) * (sxx + syy + C2);
        lsum += num / den;
    }

    // ---- Block reduction (no atomics): wave shuffle -> LDS -> partial[block] ----
    #pragma unroll
    for (int off = 32; off > 0; off >>= 1)
        lsum += __shfl_down(lsum, off, 64);
    if ((tid & 63) == 0) wavesum[tid >> 6] = lsum;
    __syncthreads();
    if (tid == 0) {
        float b = wavesum[0] + wavesum[1] + wavesum[2] + wavesum[3];
        partial[((size_t)blockIdx.z * 16 + blockIdx.y) * 4 + blockIdx.x] = (double)b;
    }
}

__global__ __launch_bounds__(256)
void ssim_finalize_kernel(const double* __restrict__ partial, float* __restrict__ out) {
    __shared__ double sh[256];
    double s = 0.0;
    for (int i = threadIdx.x; i < NBLOCKS; i += 256) s += partial[i];
    sh[threadIdx.x] = s;
    __syncthreads();
    for (int stride = 128; stride > 0; stride >>= 1) {
        if (threadIdx.x < stride) sh[threadIdx.x] += sh[threadIdx.x + stride];
        __syncthreads();
    }
    if (threadIdx.x == 0) out[0] = (float)(1.0 - sh[0] / NPIX);
}

extern "C" void kernel_launch(void* const* d_in, const int* in_sizes, int n_in,
                              void* d_out, int out_size, void* d_ws, size_t ws_size,
                              hipStream_t stream) {
    const float* x = (const float*)d_in[0];   // heatmap_clean
    const float* y = (const float*)d_in[1];   // heatmap_adv
    float* out = (float*)d_out;
    double* partial = (double*)d_ws;          // 2048 doubles = 16 KB

    // Normalized Gaussian weights, computed on host in double (identical every call).
    GaussW gw;
    double g[11], s = 0.0;
    for (int i = 0; i < 11; ++i) { double d = i - 5; g[i] = exp(-(d * d) / 4.5); s += g[i]; }
    for (int i = 0; i < 11; ++i) gw.w[i] = (float)(g[i] / s);

    dim3 grid(IMG / TILE_W, IMG / TILE_H, 32);  // (4, 16, 32)
    ssim_fused_kernel<<<grid, 256, 0, stream>>>(x, y, partial, gw);
    ssim_finalize_kernel<<<1, 256, 0, stream>>>(partial, out);
}